// Round 2
// baseline (649.270 us; speedup 1.0000x reference)
//
#include <hip/hip_runtime.h>
#include <hip/hip_bf16.h>

// DisentangledSelfAttention: B=4096, S=64, E=64, A=256, H=4, HD=64.
// Head-per-wave. Zero-LDS-scratch design: all MFMA C->fragment relayouts done
// in-register via operand-swapped MFMAs + quad redistribution (shfl), no buf.
//   T^T = M_h^T Xq^T   (A=M-frags, B=Xq-frags: same bytes as before, roles swapped)
//   L^T = Xk  T^T      (softmax reduces across quads via shfl_xor 16/32)
//   out = P V + Xq Wr + rho
// bq/bk cancel under centering; bu cancels in softmax(axis=1).

#define B_ 4096

typedef __attribute__((ext_vector_type(8))) short bf16x8;
typedef __attribute__((ext_vector_type(4))) float f32x4;

#define MFMA16(a, b, c) __builtin_amdgcn_mfma_f32_16x16x32_bf16((a), (b), (c), 0, 0, 0)

static __device__ __forceinline__ short f2b(float f) {  // RNE fp32->bf16
  union { float f; unsigned u; } x; x.f = f;
  unsigned r = x.u + 0x7fffu + ((x.u >> 16) & 1u);
  return (short)(r >> 16);
}
static __device__ __forceinline__ float b2f(short s) {
  union { unsigned u; float f; } x; x.u = ((unsigned)(unsigned short)s) << 16;
  return x.f;
}
static __device__ __forceinline__ unsigned cvtpk(float lo, float hi) {  // RNE pack
  unsigned r;
  asm volatile("v_cvt_pk_bf16_f32 %0, %1, %2" : "=v"(r) : "v"(lo), "v"(hi));
  return r;
}

// Quad redistribution: C-layout (lane holds axis2 = t*16+quad*4+r at col lc)
// -> A/B fragment (lane holds axis2 = kk*32+quad*8+j at same lc).
// pk[t][p] = packed bf16 pair (vals 4t.., p selects r={0,1} or {2,3}).
static __device__ __forceinline__ void qredist(const unsigned pk[4][2], int srcA,
                                               int srcB, int qhi, bf16x8* fr) {
  union U { unsigned u[4]; bf16x8 v; };
#pragma unroll
  for (int kk = 0; kk < 2; ++kk) {
    unsigned a0 = (unsigned)__shfl((int)pk[2 * kk][0], srcA);
    unsigned b0 = (unsigned)__shfl((int)pk[2 * kk + 1][0], srcA);
    unsigned a1 = (unsigned)__shfl((int)pk[2 * kk][1], srcA);
    unsigned b1 = (unsigned)__shfl((int)pk[2 * kk + 1][1], srcA);
    unsigned a2 = (unsigned)__shfl((int)pk[2 * kk][0], srcB);
    unsigned b2 = (unsigned)__shfl((int)pk[2 * kk + 1][0], srcB);
    unsigned a3 = (unsigned)__shfl((int)pk[2 * kk][1], srcB);
    unsigned b3 = (unsigned)__shfl((int)pk[2 * kk + 1][1], srcB);
    U x;
    x.u[0] = qhi ? b0 : a0;
    x.u[1] = qhi ? b1 : a1;
    x.u[2] = qhi ? b2 : a2;
    x.u[3] = qhi ? b3 : a3;
    fr[kk] = x.v;
  }
}

// ws layout (units: shorts)
#define MTHI 0       // [h][e'][e] = hi(M_h[e][e']), M = Wq_h Wk_h^T   (4*64*64)
#define MTLO 16384   // lo part
#define WVT  32768   // [a][e] = Wv[e][a]
#define WRT  49152   // [a][e] = Wr[e][a]
#define WU0  65536   // [h][16][64], row m=0 = Wu[:,h], rows 1..15 = 0

__global__ __launch_bounds__(256)
void prepass(const float* __restrict__ Wq, const float* __restrict__ Wk,
             const float* __restrict__ Wv, const float* __restrict__ Wr,
             const float* __restrict__ Wu, short* __restrict__ ws) {
  int t = blockIdx.x * 256 + threadIdx.x;  // 0..16383
  int a = t >> 6, e = t & 63;
  ws[WVT + t] = f2b(Wv[e * 256 + a]);
  ws[WRT + t] = f2b(Wr[e * 256 + a]);
  if (t < 4096) {
    int h = t >> 10, m = (t >> 6) & 15, e2 = t & 63;
    ws[WU0 + t] = (m == 0) ? f2b(Wu[e2 * 4 + h]) : (short)0;
  }
  // M_h[e][e'] = sum_a Wq[e, h*64+a] * Wk[e', h*64+a], stored transposed [e'][e]
  int h = t >> 12, ep = (t >> 6) & 63;
  const float* wqr = Wq + e * 256 + h * 64;
  const float* wkr = Wk + ep * 256 + h * 64;
  float s = 0.f;
#pragma unroll 8
  for (int aa = 0; aa < 64; ++aa) s += wqr[aa] * wkr[aa];
  short hi = f2b(s);
  ws[MTHI + (h * 64 + ep) * 64 + e] = hi;
  ws[MTLO + (h * 64 + ep) * 64 + e] = f2b(s - b2f(hi));
}

__global__ __launch_bounds__(256, 3)
void attn_main(const float* __restrict__ query, const float* __restrict__ key_,
               const float* __restrict__ value, const float* __restrict__ bv,
               const float* __restrict__ br, const short* __restrict__ ws,
               float* __restrict__ out) {
  const int b    = blockIdx.x;
  const int tid  = threadIdx.x;
  const int w    = tid >> 6;    // wave id == head id
  const int lane = tid & 63;
  const int quad = lane >> 4;
  const int lc   = lane & 15;
  const int h    = w;
  const int qhi  = quad >> 1;
  const int srcA = lc + 32 * (quad & 1);
  const int srcB = srcA + 16;

  __shared__ short XqH[64][72];     // centered query, hi bf16
  __shared__ short XqL[64][72];     // centered query, lo bf16
  __shared__ short Xk [64][72];     // centered key, single bf16
  __shared__ float colsq[4][64];
  __shared__ float colsk[4][64];
  __shared__ float mq[64];          // query column means (for rho)
  // total LDS = 3*9216 + 2*1024 + 256 = 29952 B  (was 67072)

  // ================= centering phase (2 barriers, then barrier-free) ========
  const int crow = w * 16 + (lane >> 2);   // row this lane loads
  const int cg   = (lane & 3) * 16;        // col group base
  const float* qp = query + ((size_t)b * 64 + crow) * 64 + cg;
  const float* kp = key_  + ((size_t)b * 64 + crow) * 64 + cg;
  f32x4 qv[4], kv[4];
#pragma unroll
  for (int j = 0; j < 4; ++j) { qv[j] = *(const f32x4*)(qp + 4 * j); kv[j] = *(const f32x4*)(kp + 4 * j); }

  f32x4 sq[4], sk[4];
#pragma unroll
  for (int j = 0; j < 4; ++j) { sq[j] = qv[j]; sk[j] = kv[j]; }
#pragma unroll
  for (int off = 4; off <= 32; off <<= 1)
#pragma unroll
    for (int j = 0; j < 4; ++j)
#pragma unroll
      for (int c = 0; c < 4; ++c) {
        sq[j][c] += __shfl_xor(sq[j][c], off);
        sk[j][c] += __shfl_xor(sk[j][c], off);
      }
  if ((lane & 60) == 0) {
#pragma unroll
    for (int j = 0; j < 4; ++j) {
      *(f32x4*)&colsq[w][cg + 4 * j] = sq[j];
      *(f32x4*)&colsk[w][cg + 4 * j] = sk[j];
    }
  }
  __syncthreads();  // barrier 1

  f32x4 mqv[4], mkv[4];
#pragma unroll
  for (int j = 0; j < 4; ++j) {
    f32x4 aq = {0.f, 0.f, 0.f, 0.f}, ak = {0.f, 0.f, 0.f, 0.f};
#pragma unroll
    for (int ww = 0; ww < 4; ++ww) {
      aq += *(const f32x4*)&colsq[ww][cg + 4 * j];
      ak += *(const f32x4*)&colsk[ww][cg + 4 * j];
    }
    mqv[j] = aq * (1.0f / 64.0f);
    mkv[j] = ak * (1.0f / 64.0f);
  }
  if (w == 0 && (lane & 60) == 0)
#pragma unroll
    for (int j = 0; j < 4; ++j) *(f32x4*)&mq[cg + 4 * j] = mqv[j];

#pragma unroll
  for (int half = 0; half < 2; ++half) {
    bf16x8 qh8, ql8, k8;
#pragma unroll
    for (int jj = 0; jj < 8; ++jj) {
      int j = half * 2 + (jj >> 2), c = jj & 3;
      float cq = qv[j][c] - mqv[j][c];
      short hi = f2b(cq);
      qh8[jj] = hi;
      ql8[jj] = f2b(cq - b2f(hi));
      k8[jj]  = f2b(kv[j][c] - mkv[j][c]);
    }
    *(bf16x8*)&XqH[crow][cg + 8 * half] = qh8;
    *(bf16x8*)&XqL[crow][cg + 8 * half] = ql8;
    *(bf16x8*)&Xk [crow][cg + 8 * half] = k8;
  }
  __syncthreads();  // barrier 2: Xc buffers + mq visible. No more barriers.

  // ================= per-head phase (wave-private, barrier-free) ============
  // value A-fragments (issued early to hide HBM latency)
  bf16x8 xv[4][2];
#pragma unroll
  for (int mt = 0; mt < 4; ++mt)
#pragma unroll
    for (int kk = 0; kk < 2; ++kk) {
      const float* vp = value + ((size_t)b * 64 + mt * 16 + lc) * 64 + kk * 32 + quad * 8;
      f32x4 v0 = *(const f32x4*)vp, v1 = *(const f32x4*)(vp + 4);
      union { unsigned u[4]; bf16x8 v; } pkv;
      pkv.u[0] = cvtpk(v0[0], v0[1]);
      pkv.u[1] = cvtpk(v0[2], v0[3]);
      pkv.u[2] = cvtpk(v1[0], v1[1]);
      pkv.u[3] = cvtpk(v1[2], v1[3]);
      xv[mt][kk] = pkv.v;
    }

  // rho[d=lane] = mu_q . Wr[:, h*64+lane] + br[h*64+lane]
  float rho;
  {
    const short* wrr = ws + WRT + (h * 64 + lane) * 64;
    float acc = br[h * 64 + lane];
#pragma unroll
    for (int e8 = 0; e8 < 8; ++e8) {
      bf16x8 w8 = *(const bf16x8*)(wrr + e8 * 8);
#pragma unroll
      for (int j = 0; j < 8; ++j) acc += mq[e8 * 8 + j] * b2f(w8[j]);
    }
    rho = acc;
  }

  // ---- unary: u = softmax_s( Xck @ Wu[:,h] ) -> un[nt] = u[nt*16+lc] ----
  float usm[4];
  {
    bf16x8 wu[2];
#pragma unroll
    for (int kk = 0; kk < 2; ++kk)
      wu[kk] = *(const bf16x8*)(ws + WU0 + h * 1024 + lc * 64 + kk * 32 + quad * 8);
    f32x4 aU[4];
#pragma unroll
    for (int nt = 0; nt < 4; ++nt) {
      aU[nt] = f32x4{0.f, 0.f, 0.f, 0.f};
#pragma unroll
      for (int kk = 0; kk < 2; ++kk) {
        bf16x8 xb = *(const bf16x8*)&Xk[nt * 16 + lc][kk * 32 + quad * 8];
        aU[nt] = MFMA16(wu[kk], xb, aU[nt]);
      }
    }
    float un[4];
#pragma unroll
    for (int nt = 0; nt < 4; ++nt) un[nt] = __shfl(aU[nt][0], lc);
    float um = fmaxf(fmaxf(un[0], un[1]), fmaxf(un[2], un[3]));
    um = fmaxf(um, __shfl_xor(um, 1)); um = fmaxf(um, __shfl_xor(um, 2));
    um = fmaxf(um, __shfl_xor(um, 4)); um = fmaxf(um, __shfl_xor(um, 8));
    float ue[4], us = 0.f;
#pragma unroll
    for (int nt = 0; nt < 4; ++nt) { ue[nt] = __expf(un[nt] - um); us += ue[nt]; }
    us += __shfl_xor(us, 1); us += __shfl_xor(us, 2);
    us += __shfl_xor(us, 4); us += __shfl_xor(us, 8);
    float uinv = __builtin_amdgcn_rcpf(us);
#pragma unroll
    for (int nt = 0; nt < 4; ++nt) usm[nt] = ue[nt] * uinv;   // u[nt*16+lc]
  }

  // ---- T^T = M_h^T @ Xq^T (3-term hi/lo) -> tB fragments in-register ----
  bf16x8 tB[4][2];
#pragma unroll
  for (int mtq = 0; mtq < 4; ++mtq) {
    bf16x8 xqh[2], xql[2];
#pragma unroll
    for (int kk = 0; kk < 2; ++kk) {
      xqh[kk] = *(const bf16x8*)&XqH[mtq * 16 + lc][kk * 32 + quad * 8];
      xql[kk] = *(const bf16x8*)&XqL[mtq * 16 + lc][kk * 32 + quad * 8];
    }
    f32x4 att[4];
#pragma unroll
    for (int nt = 0; nt < 4; ++nt) {
      att[nt] = f32x4{0.f, 0.f, 0.f, 0.f};
#pragma unroll
      for (int kk = 0; kk < 2; ++kk) {
        int off = h * 4096 + (nt * 16 + lc) * 64 + kk * 32 + quad * 8;
        bf16x8 mh = *(const bf16x8*)(ws + MTHI + off);
        bf16x8 ml = *(const bf16x8*)(ws + MTLO + off);
        att[nt] = MFMA16(mh, xqh[kk], att[nt]);
        att[nt] = MFMA16(ml, xqh[kk], att[nt]);
        att[nt] = MFMA16(mh, xql[kk], att[nt]);
      }
    }
    unsigned pk[4][2];
#pragma unroll
    for (int t = 0; t < 4; ++t) {
      pk[t][0] = cvtpk(att[t][0], att[t][1]);
      pk[t][1] = cvtpk(att[t][2], att[t][3]);
    }
    qredist(pk, srcA, srcB, qhi, tB[mtq]);
  }

  // ---- L^T = Xk @ T^T : aLT[mtk][mtq], lane holds L[q=mtq*16+lc][k=mtk*16+quad*4+r]
  f32x4 aLT[4][4];
#pragma unroll
  for (int mtk = 0; mtk < 4; ++mtk)
#pragma unroll
    for (int mtq = 0; mtq < 4; ++mtq) aLT[mtk][mtq] = f32x4{0.f, 0.f, 0.f, 0.f};
#pragma unroll
  for (int mtk = 0; mtk < 4; ++mtk)
#pragma unroll
    for (int kk = 0; kk < 2; ++kk) {
      bf16x8 xkf = *(const bf16x8*)&Xk[mtk * 16 + lc][kk * 32 + quad * 8];
#pragma unroll
      for (int mtq = 0; mtq < 4; ++mtq)
        aLT[mtk][mtq] = MFMA16(xkf, tB[mtq][kk], aLT[mtk][mtq]);
    }

  // unary values at this lane's k coords: ush[mtk][r] = u[mtk*16+quad*4+r]
  float ush[4][4];
#pragma unroll
  for (int mtk = 0; mtk < 4; ++mtk)
#pragma unroll
    for (int r = 0; r < 4; ++r) ush[mtk][r] = __shfl(usm[mtk], quad * 4 + r);

  // ---- softmax over k (in-lane 16 + cross-quad shfl) ; P -> pA fragments ----
  bf16x8 pA[4][2];
#pragma unroll
  for (int mtq = 0; mtq < 4; ++mtq) {
    float m = aLT[0][mtq][0];
#pragma unroll
    for (int mtk = 0; mtk < 4; ++mtk)
#pragma unroll
      for (int r = 0; r < 4; ++r) m = fmaxf(m, aLT[mtk][mtq][r]);
    m = fmaxf(m, __shfl_xor(m, 16));
    m = fmaxf(m, __shfl_xor(m, 32));
    float e[4][4], s = 0.f;
#pragma unroll
    for (int mtk = 0; mtk < 4; ++mtk)
#pragma unroll
      for (int r = 0; r < 4; ++r) { e[mtk][r] = __expf(aLT[mtk][mtq][r] - m); s += e[mtk][r]; }
    s += __shfl_xor(s, 16);
    s += __shfl_xor(s, 32);
    float inv = __builtin_amdgcn_rcpf(s);
    unsigned pk[4][2];
#pragma unroll
    for (int mtk = 0; mtk < 4; ++mtk) {
      float p0 = e[mtk][0] * inv + ush[mtk][0];
      float p1 = e[mtk][1] * inv + ush[mtk][1];
      float p2 = e[mtk][2] * inv + ush[mtk][2];
      float p3 = e[mtk][3] * inv + ush[mtk][3];
      pk[mtk][0] = cvtpk(p0, p1);
      pk[mtk][1] = cvtpk(p2, p3);
    }
    qredist(pk, srcA, srcB, qhi, pA[mtq]);
  }

  // ---- V = Xv @ Wv_h + bv -> vB fragments in-register ----
  bf16x8 vB[4][2];
#pragma unroll
  for (int nt = 0; nt < 4; ++nt) {
    bf16x8 wv[2];
#pragma unroll
    for (int kk = 0; kk < 2; ++kk)
      wv[kk] = *(const bf16x8*)(ws + WVT + (h * 64 + nt * 16 + lc) * 64 + kk * 32 + quad * 8);
    f32x4 av[4];
#pragma unroll
    for (int mtk = 0; mtk < 4; ++mtk) {
      av[mtk] = f32x4{0.f, 0.f, 0.f, 0.f};
#pragma unroll
      for (int kk = 0; kk < 2; ++kk) av[mtk] = MFMA16(xv[mtk][kk], wv[kk], av[mtk]);
    }
    float bvv = bv[h * 64 + nt * 16 + lc];
    unsigned pk[4][2];
#pragma unroll
    for (int mtk = 0; mtk < 4; ++mtk) {
      pk[mtk][0] = cvtpk(av[mtk][0] + bvv, av[mtk][1] + bvv);
      pk[mtk][1] = cvtpk(av[mtk][2] + bvv, av[mtk][3] + bvv);
    }
    qredist(pk, srcA, srcB, qhi, vB[nt]);
  }

  float rr[4];
#pragma unroll
  for (int nt = 0; nt < 4; ++nt) rr[nt] = __shfl(rho, nt * 16 + lc);

  // ---- out = P @ V + Xcq @ Wr_h (2-term) + rho ----
#pragma unroll
  for (int mt = 0; mt < 4; ++mt) {
    bf16x8 xh[2], xl[2];
#pragma unroll
    for (int kk = 0; kk < 2; ++kk) {
      xh[kk] = *(const bf16x8*)&XqH[mt * 16 + lc][kk * 32 + quad * 8];
      xl[kk] = *(const bf16x8*)&XqL[mt * 16 + lc][kk * 32 + quad * 8];
    }
#pragma unroll
    for (int nt = 0; nt < 4; ++nt) {
      f32x4 acc = {0.f, 0.f, 0.f, 0.f};
#pragma unroll
      for (int kk = 0; kk < 2; ++kk) {
        acc = MFMA16(pA[mt][kk], vB[nt][kk], acc);
        bf16x8 wr8 = *(const bf16x8*)(ws + WRT + (h * 64 + nt * 16 + lc) * 64 + kk * 32 + quad * 8);
        acc = MFMA16(xh[kk], wr8, acc);
        acc = MFMA16(xl[kk], wr8, acc);
      }
      float* op = out + ((size_t)b * 64 + mt * 16 + quad * 4) * 256 + h * 64 + nt * 16 + lc;
#pragma unroll
      for (int r = 0; r < 4; ++r) op[(size_t)r * 256] = acc[r] + rr[nt];
    }
  }
}

extern "C" void kernel_launch(void* const* d_in, const int* in_sizes, int n_in,
                              void* d_out, int out_size, void* d_ws, size_t ws_size,
                              hipStream_t stream) {
  (void)in_sizes; (void)n_in; (void)out_size; (void)ws_size;
  const float* query = (const float*)d_in[0];
  const float* key_  = (const float*)d_in[1];
  const float* value = (const float*)d_in[2];
  const float* Wq    = (const float*)d_in[3];
  // d_in[4] = bq: cancels under mean-centering
  const float* Wk    = (const float*)d_in[5];
  // d_in[6] = bk: cancels under mean-centering
  const float* Wv    = (const float*)d_in[7];
  const float* bv    = (const float*)d_in[8];
  const float* Wu    = (const float*)d_in[9];
  // d_in[10] = bu: cancels in softmax over fields
  const float* Wr    = (const float*)d_in[11];
  const float* br    = (const float*)d_in[12];
  short* ws = (short*)d_ws;

  hipLaunchKernelGGL(prepass, dim3(64), dim3(256), 0, stream, Wq, Wk, Wv, Wr, Wu, ws);
  hipLaunchKernelGGL(attn_main, dim3(B_), dim3(256), 0, stream,
                     query, key_, value, bv, br, ws, (float*)d_out);
}